// Round 2
// baseline (1166.744 us; speedup 1.0000x reference)
//
#include <hip/hip_runtime.h>

#define E_TOTAL 800000
#define NN 50000
#define MSG_BYTES (NN * 64 * 4)

typedef unsigned short u16;
typedef short short8 __attribute__((ext_vector_type(8)));
typedef float floatx4 __attribute__((ext_vector_type(4)));

__device__ __forceinline__ u16 f2bf(float f) {
    union { float f; unsigned int i; } x; x.f = f;
    unsigned int i = x.i;
    return (u16)((i + 0x7FFFu + ((i >> 16) & 1u)) >> 16);  // RNE
}
__device__ __forceinline__ unsigned int pack2(float a, float b) {
    return (unsigned int)f2bf(a) | ((unsigned int)f2bf(b) << 16);
}
// load float4, convert to 4 bf16 packed in uint2
__device__ __forceinline__ uint2 cvt4(const float* p) {
    float4 v = *(const float4*)p;
    uint2 r; r.x = pack2(v.x, v.y); r.y = pack2(v.z, v.w);
    return r;
}

// ---- one MLP layer on a 16-row slab owned by one wave --------------------
// lds_in/lds_out: wave slab base (bf16). wt: [N][K] bf16 k-contig. bias: f32.
template<int K, int N, bool RELU>
__device__ __forceinline__ void layer_slab(const u16* lds_in, int in_stride,
                                           u16* lds_out, int out_stride,
                                           const u16* __restrict__ wt,
                                           const float* __restrict__ bias,
                                           int lane)
{
    const int m = lane & 15, quad = lane >> 4;
    short8 a[K / 32];
#pragma unroll
    for (int kb = 0; kb < K / 32; ++kb)
        a[kb] = *(const short8*)(lds_in + m * in_stride + kb * 32 + quad * 8);
#pragma unroll
    for (int nt = 0; nt < N / 16; nt += 2) {
        floatx4 acc0 = {0.f, 0.f, 0.f, 0.f}, acc1 = {0.f, 0.f, 0.f, 0.f};
        const int n0 = nt * 16 + m, n1 = n0 + 16;
        const u16* w0 = wt + n0 * K + quad * 8;
        const u16* w1 = wt + n1 * K + quad * 8;
#pragma unroll
        for (int kb = 0; kb < K / 32; ++kb) {
            short8 b0 = *(const short8*)(w0 + kb * 32);
            short8 b1 = *(const short8*)(w1 + kb * 32);
            acc0 = __builtin_amdgcn_mfma_f32_16x16x32_bf16(a[kb], b0, acc0, 0, 0, 0);
            acc1 = __builtin_amdgcn_mfma_f32_16x16x32_bf16(a[kb], b1, acc1, 0, 0, 0);
        }
        float bb0 = bias[n0], bb1 = bias[n1];
#pragma unroll
        for (int r = 0; r < 4; ++r) {
            int row = quad * 4 + r;
            float v0 = acc0[r] + bb0, v1 = acc1[r] + bb1;
            if (RELU) { v0 = fmaxf(v0, 0.f); v1 = fmaxf(v1, 0.f); }
            lds_out[row * out_stride + n0] = f2bf(v0);
            lds_out[row * out_stride + n1] = f2bf(v1);
        }
    }
}

// ---- weight prep: W[k][n] f32 -> Wt[n][k] bf16, all 8 matrices ------------
__global__ __launch_bounds__(256) void prep_wt(
    const float* __restrict__ e0, const float* __restrict__ e1,
    const float* __restrict__ e2, const float* __restrict__ e3,
    const float* __restrict__ m0, const float* __restrict__ m1,
    const float* __restrict__ m2, const float* __restrict__ m3,
    u16* __restrict__ dst)
{
    int t = blockIdx.x * 256 + threadIdx.x;
    if (t >= 122880) return;
    const int offs[9] = {0, 24576, 40960, 57344, 65536, 81920, 98304, 114688, 122880};
    const int Ks[8]   = {192, 128, 128, 128, 128, 128, 128, 128};
    const int Ns[8]   = {128, 128, 128,  64, 128, 128, 128,  64};
    const float* srcs[8] = {e0, e1, e2, e3, m0, m1, m2, m3};
    int s = 0;
    while (t >= offs[s + 1]) ++s;
    int e = t - offs[s];
    int K = Ks[s], N = Ns[s];
    int n = e / K, k = e - n * K;
    dst[t] = f2bf(srcs[s][k * N + n]);
}

// ---- edge kernel: 64 edges per block, fused 4-layer MLP + scatter ---------
__global__ __launch_bounds__(256) void edge_kernel(
    const float* __restrict__ h, const int* __restrict__ eidx,
    const float* __restrict__ ea, const u16* __restrict__ wt,
    const float* __restrict__ eb0, const float* __restrict__ eb1,
    const float* __restrict__ eb2, const float* __restrict__ eb3,
    float* __restrict__ msg, float* __restrict__ out_edge)
{
    __shared__ u16 Xs[64 * 200];   // [64][192] pad->200
    __shared__ u16 Ha[64 * 136];   // [64][128] pad->136
    __shared__ u16 Hb[64 * 136];
    __shared__ int row_s[64], col_s[64];

    const int tid = threadIdx.x;
    const int ebase = blockIdx.x * 64;

    if (tid < 64)       row_s[tid] = eidx[ebase + tid];
    else if (tid < 128) col_s[tid - 64] = eidx[E_TOTAL + ebase + (tid - 64)];
    __syncthreads();

    // gather + f32->bf16: cols 0..63 = h[row], 64..127 = h[col], 128..191 = ea
#pragma unroll
    for (int g = tid; g < 1024; g += 256) {
        int e = g >> 4, c = g & 15;
        *(uint2*)&Xs[e * 200 + c * 4] = cvt4(h + (size_t)row_s[e] * 64 + c * 4);
    }
#pragma unroll
    for (int g = tid; g < 1024; g += 256) {
        int e = g >> 4, c = g & 15;
        *(uint2*)&Xs[e * 200 + 64 + c * 4] = cvt4(h + (size_t)col_s[e] * 64 + c * 4);
    }
#pragma unroll
    for (int g = tid; g < 1024; g += 256) {
        int e = g >> 4, c = g & 15;
        *(uint2*)&Xs[e * 200 + 128 + c * 4] = cvt4(ea + (size_t)(ebase + e) * 64 + c * 4);
    }
    __syncthreads();

    const int wave = tid >> 6, lane = tid & 63;
    const int w16 = wave * 16;
    const u16* wtE0 = wt;
    const u16* wtE1 = wt + 24576;
    const u16* wtE2 = wt + 40960;
    const u16* wtE3 = wt + 57344;

    // wave-private row slabs: no inter-layer barriers needed
    layer_slab<192, 128, true>(Xs + w16 * 200, 200, Ha + w16 * 136, 136, wtE0, eb0, lane);
    layer_slab<128, 128, true>(Ha + w16 * 136, 136, Hb + w16 * 136, 136, wtE1, eb1, lane);
    layer_slab<128, 128, true>(Hb + w16 * 136, 136, Ha + w16 * 136, 136, wtE2, eb2, lane);

    // final layer K=128 N=64, no relu; write edge_out + atomic scatter to msg
    {
        const u16* in = Ha + w16 * 136;
        const int m = lane & 15, quad = lane >> 4;
        short8 a[4];
#pragma unroll
        for (int kb = 0; kb < 4; ++kb)
            a[kb] = *(const short8*)(in + m * 136 + kb * 32 + quad * 8);
#pragma unroll
        for (int np = 0; np < 2; ++np) {
            floatx4 acc0 = {0, 0, 0, 0}, acc1 = {0, 0, 0, 0};
            const int n0 = np * 32 + m, n1 = n0 + 16;
#pragma unroll
            for (int kb = 0; kb < 4; ++kb) {
                short8 b0 = *(const short8*)(wtE3 + n0 * 128 + kb * 32 + quad * 8);
                short8 b1 = *(const short8*)(wtE3 + n1 * 128 + kb * 32 + quad * 8);
                acc0 = __builtin_amdgcn_mfma_f32_16x16x32_bf16(a[kb], b0, acc0, 0, 0, 0);
                acc1 = __builtin_amdgcn_mfma_f32_16x16x32_bf16(a[kb], b1, acc1, 0, 0, 0);
            }
            float bb0 = eb3[n0], bb1 = eb3[n1];
#pragma unroll
            for (int r = 0; r < 4; ++r) {
                int rl = w16 + quad * 4 + r;
                size_t e = (size_t)(ebase + rl);
                float v0 = acc0[r] + bb0, v1 = acc1[r] + bb1;
                out_edge[e * 64 + n0] = v0;
                out_edge[e * 64 + n1] = v1;
                float* mrow = msg + (size_t)col_s[rl] * 64;
                atomicAdd(mrow + n0, v0);
                atomicAdd(mrow + n1, v1);
            }
        }
    }
}

// ---- node kernel: 64 nodes per block ---------------------------------------
__global__ __launch_bounds__(256) void node_kernel(
    const float* __restrict__ h, const float* __restrict__ msg,
    const u16* __restrict__ wt,
    const float* __restrict__ nb0, const float* __restrict__ nb1,
    const float* __restrict__ nb2, const float* __restrict__ nb3,
    float* __restrict__ out_node)
{
    __shared__ u16 Xs[64 * 136];
    __shared__ u16 Ha[64 * 136];
    __shared__ u16 Hb[64 * 136];

    const int tid = threadIdx.x;
    const int nbase = blockIdx.x * 64;

#pragma unroll
    for (int g = tid; g < 1024; g += 256) {
        int e = g >> 4, c = g & 15;
        int node = nbase + e;
        uint2 v = {0u, 0u};
        if (node < NN) v = cvt4(h + (size_t)node * 64 + c * 4);
        *(uint2*)&Xs[e * 136 + c * 4] = v;
    }
#pragma unroll
    for (int g = tid; g < 1024; g += 256) {
        int e = g >> 4, c = g & 15;
        int node = nbase + e;
        uint2 v = {0u, 0u};
        if (node < NN) v = cvt4(msg + (size_t)node * 64 + c * 4);
        *(uint2*)&Xs[e * 136 + 64 + c * 4] = v;
    }
    __syncthreads();

    const int wave = tid >> 6, lane = tid & 63;
    const int w16 = wave * 16;
    const u16* wtN0 = wt + 65536;
    const u16* wtN1 = wt + 81920;
    const u16* wtN2 = wt + 98304;
    const u16* wtN3 = wt + 114688;

    layer_slab<128, 128, true>(Xs + w16 * 136, 136, Ha + w16 * 136, 136, wtN0, nb0, lane);
    layer_slab<128, 128, true>(Ha + w16 * 136, 136, Hb + w16 * 136, 136, wtN1, nb1, lane);
    layer_slab<128, 128, true>(Hb + w16 * 136, 136, Ha + w16 * 136, 136, wtN2, nb2, lane);

    {
        const u16* in = Ha + w16 * 136;
        const int m = lane & 15, quad = lane >> 4;
        short8 a[4];
#pragma unroll
        for (int kb = 0; kb < 4; ++kb)
            a[kb] = *(const short8*)(in + m * 136 + kb * 32 + quad * 8);
#pragma unroll
        for (int np = 0; np < 2; ++np) {
            floatx4 acc0 = {0, 0, 0, 0}, acc1 = {0, 0, 0, 0};
            const int n0 = np * 32 + m, n1 = n0 + 16;
#pragma unroll
            for (int kb = 0; kb < 4; ++kb) {
                short8 b0 = *(const short8*)(wtN3 + n0 * 128 + kb * 32 + quad * 8);
                short8 b1 = *(const short8*)(wtN3 + n1 * 128 + kb * 32 + quad * 8);
                acc0 = __builtin_amdgcn_mfma_f32_16x16x32_bf16(a[kb], b0, acc0, 0, 0, 0);
                acc1 = __builtin_amdgcn_mfma_f32_16x16x32_bf16(a[kb], b1, acc1, 0, 0, 0);
            }
            float bb0 = nb3[n0], bb1 = nb3[n1];
#pragma unroll
            for (int r = 0; r < 4; ++r) {
                int rl = w16 + quad * 4 + r;
                int node = nbase + rl;
                if (node < NN) {
                    out_node[(size_t)node * 64 + n0] = acc0[r] + bb0;
                    out_node[(size_t)node * 64 + n1] = acc1[r] + bb1;
                }
            }
        }
    }
}

extern "C" void kernel_launch(void* const* d_in, const int* in_sizes, int n_in,
                              void* d_out, int out_size, void* d_ws, size_t ws_size,
                              hipStream_t stream)
{
    // setup_inputs() dict order: h, edge_index, edge_attr, then per i:
    // ew{i}, eb{i}, nw{i}, nb{i}
    const float* h   = (const float*)d_in[0];
    const int* eidx  = (const int*)d_in[1];
    const float* ea  = (const float*)d_in[2];
    const float* ew0 = (const float*)d_in[3];
    const float* eb0 = (const float*)d_in[4];
    const float* nw0 = (const float*)d_in[5];
    const float* nb0 = (const float*)d_in[6];
    const float* ew1 = (const float*)d_in[7];
    const float* eb1 = (const float*)d_in[8];
    const float* nw1 = (const float*)d_in[9];
    const float* nb1 = (const float*)d_in[10];
    const float* ew2 = (const float*)d_in[11];
    const float* eb2 = (const float*)d_in[12];
    const float* nw2 = (const float*)d_in[13];
    const float* nb2 = (const float*)d_in[14];
    const float* ew3 = (const float*)d_in[15];
    const float* eb3 = (const float*)d_in[16];
    const float* nw3 = (const float*)d_in[17];
    const float* nb3 = (const float*)d_in[18];

    float* msg = (float*)d_ws;
    u16* wt    = (u16*)((char*)d_ws + MSG_BYTES);
    float* out_node = (float*)d_out;
    float* out_edge = out_node + (size_t)NN * 64;

    hipMemsetAsync(d_ws, 0, MSG_BYTES, stream);
    prep_wt<<<480, 256, 0, stream>>>(ew0, ew1, ew2, ew3, nw0, nw1, nw2, nw3, wt);
    edge_kernel<<<E_TOTAL / 64, 256, 0, stream>>>(h, eidx, ea, wt,
                                                  eb0, eb1, eb2, eb3, msg, out_edge);
    node_kernel<<<(NN + 63) / 64, 256, 0, stream>>>(h, msg, wt,
                                                    nb0, nb1, nb2, nb3, out_node);
}